// Round 14
// baseline (279.132 us; speedup 1.0000x reference)
//
#include <hip/hip_runtime.h>

#define T_SEQ 512
#define BATCH 4096
#define D_IN  5
#define H     15
#define G4    60   // 4*H
#define OUTN  25
#define XW_BYTES (T_SEQ * G4 * 4)     // 122880
#define H1_BYTES (T_SEQ * 16 * 4)     // 32768
#define PROBE_T 128

#define M_SIG  (-1.4426950408889634f)   // sigmoid exp2 prescale
#define M_TANH (-2.8853901f)            // tanh exp2 prescale (-2*log2e)

// ---------- helpers ----------
__device__ __forceinline__ float fast_exp2(float x) {
#if __has_builtin(__builtin_amdgcn_exp2f)
  return __builtin_amdgcn_exp2f(x);
#else
  return exp2f(x);
#endif
}
__device__ __forceinline__ float fast_rcp(float x) {
#if __has_builtin(__builtin_amdgcn_rcpf)
  return __builtin_amdgcn_rcpf(x);
#else
  return 1.0f / x;
#endif
}
__device__ __forceinline__ float rl(float v, int lane) {
  return __int_as_float(__builtin_amdgcn_readlane(__float_as_int(v), lane));
}
template <int K>
__device__ __forceinline__ float qbcast(float v) {
  return __int_as_float(__builtin_amdgcn_update_dpp(
      0, __float_as_int(v), K * 0x55, 0xF, 0xF, true));
}

// ---------- kernel A: xw0[t][g] = (x[t,B-1,:]·w_ih0[g,:] + biases) * m(g) ----
__global__ void precompute_xw0(const float* __restrict__ x,
                               const float* __restrict__ w_ih0,
                               const float* __restrict__ b_ih0,
                               const float* __restrict__ b_hh0,
                               float* __restrict__ xw0) {
  int idx = blockIdx.x * blockDim.x + threadIdx.x;
  if (idx >= T_SEQ * G4) return;
  int t = idx / G4;
  int g = idx - t * G4;
  const float* xp = x + ((size_t)t * BATCH + (BATCH - 1)) * D_IN;
  float a = b_ih0[g] + b_hh0[g];
#pragma unroll
  for (int d = 0; d < D_IN; ++d) a = fmaf(xp[d], w_ih0[g * D_IN + d], a);
  float m = (g / H == 2) ? M_TANH : M_SIG;
  xw0[idx] = a * m;
}

// ---------- probe 1: pure ISSUE floor ----------
// r8's per-step instruction mix (60 FMA + 4 exp + 4 rcp + 8 DPP + 30 readlane
// + 1 global load) with ALL dependencies broken. dur_us/PROBE_T = issue cost.
__global__ void __launch_bounds__(64, 1)
probe_issue(const float* __restrict__ xw0) {
  const int lane = threadIdx.x;
  const int gidx = lane % 60;
  float acc0 = xw0[lane], acc1 = acc0 + 1.0f, acc2 = acc0 + 2.0f;
  float acc3 = acc0 + 3.0f, acc4 = acc0 + 4.0f, acc5 = acc0 + 5.0f;
  float r0 = xw0[64 + lane];
  float w0v = xw0[128 + lane];
  float xw_prev = xw0[lane];
  const float c0 = 1.000001f, c1 = 0.999999f, c2 = 1.000002f;
  const float c3 = 0.999998f, c4 = 1.000003f, c5 = 0.999997f;

  for (int t = 0; t < PROBE_T; ++t) {
    float xw = xw0[t * G4 + gidx];               // 1 load (latency-covered)
#pragma unroll
    for (int k = 0; k < 10; ++k) {               // 60 FMA, 6 indep chains
      acc0 = fmaf(xw_prev, c0, acc0);
      acc1 = fmaf(xw_prev, c1, acc1);
      acc2 = fmaf(r0,      c2, acc2);
      acc3 = fmaf(r0,      c3, acc3);
      acc4 = fmaf(w0v,     c4, acc4);
      acc5 = fmaf(w0v,     c5, acc5);
    }
    // 4 exp + 4 rcp, independent inputs (stable regs)
    float e0 = fast_exp2(xw_prev), e1 = fast_exp2(r0);
    float e2 = fast_exp2(w0v),     e3 = fast_exp2(xw_prev);
    float q0 = fast_rcp(xw_prev),  q1 = fast_rcp(r0);
    float q2 = fast_rcp(w0v),      q3 = fast_rcp(xw_prev);
    // 8 DPP
    float d0 = qbcast<0>(xw_prev), d1 = qbcast<1>(xw_prev);
    float d2 = qbcast<2>(xw_prev), d3 = qbcast<3>(xw_prev);
    float d4 = qbcast<0>(r0),      d5 = qbcast<1>(r0);
    float d6 = qbcast<2>(r0),      d7 = qbcast<3>(r0);
    // 30 readlane of an old reg (no write hazard)
#pragma unroll
    for (int k = 0; k < 30; ++k) {
      int ri = __builtin_amdgcn_readlane(__float_as_int(r0), k);
      asm volatile("" :: "s"(ri));
    }
    asm volatile("" :: "v"(e0), "v"(e1), "v"(e2), "v"(e3),
                       "v"(q0), "v"(q1), "v"(q2), "v"(q3),
                       "v"(d0), "v"(d1), "v"(d2), "v"(d3),
                       "v"(d4), "v"(d5), "v"(d6), "v"(d7));
    xw_prev = xw;
  }
  asm volatile("" :: "v"(acc0), "v"(acc1), "v"(acc2),
                     "v"(acc3), "v"(acc4), "v"(acc5));
}

// ---------- probe 2: pure CHAIN floor ----------
// Only the loop-carried L0 cycle: 5-FMA acc chain -> combine -> exp -> rcp ->
// fma -> DPP -> c-update -> exp -> rcp -> fma -> mul -> readlane -> feeds next.
__global__ void __launch_bounds__(64, 1)
probe_chain(const float* __restrict__ xw0) {
  const int lane = threadIdx.x;
  float w0 = xw0[lane] * 0.01f, w1 = xw0[64 + lane] * 0.01f;
  float sh = xw0[128 + lane];
  float c  = 0.0f;
  for (int t = 0; t < PROBE_T; ++t) {
    float a = 0.1f;
    a = fmaf(w0, sh, a); a = fmaf(w1, sh, a); a = fmaf(w0, sh, a);
    a = fmaf(w1, sh, a); a = fmaf(w0, sh, a);            // 5-FMA chain
    float e  = fast_exp2(a);
    float s  = fast_rcp(1.0f + e);
    float v  = fmaf(s, -0.5f, 0.25f);
    float vb = qbcast<1>(v);
    c = fmaf(vb, c, v * vb);
    float ec = fast_exp2(c);
    float th = fmaf(fast_rcp(1.0f + ec), 2.0f, -1.0f);
    float h  = vb * th;
    sh = rl(h, 4 * (t & 7));                             // readlane closes cycle
  }
  asm volatile("" :: "v"(sh), "v"(c));
}

// ---------- kernel B: r8 stage-skewed serial LSTM, LIN offloaded ----------
__global__ void __launch_bounds__(64, 1)
lstm_main(const float* __restrict__ xw0,
          const float* __restrict__ w_hh0,
          const float* __restrict__ w_ih1,
          const float* __restrict__ w_hh1,
          const float* __restrict__ b_ih1,
          const float* __restrict__ b_hh1,
          const float* __restrict__ w_lin,
          const float* __restrict__ b_lin,
          float* __restrict__ out,
          float* __restrict__ h1g) {
  const int lane = threadIdx.x;
  const int ty = lane & 3;
  const int j  = lane >> 2;
  const int g  = (j < H) ? (ty * H + j) : 0;

  const bool  isT  = (ty == 2);
  const float m    = isT ? M_TANH : M_SIG;
  const float scv  = isT ? (2.0f * M_TANH) : 1.0f;
  const float offv = isT ? (-M_TANH) : 0.0f;

  float w0[H], wi1[H], wh1[H];
#pragma unroll
  for (int k = 0; k < H; ++k) {
    w0[k]  = w_hh0[g * H + k] * m;
    wi1[k] = w_ih1[g * H + k] * m;
    wh1[k] = w_hh1[g * H + k] * m;
  }
  const float bias1 = (b_ih1[g] + b_hh1[g]) * m;

  float wl[H];
  {
    int o = (lane < OUTN) ? lane : 0;
#pragma unroll
    for (int k = 0; k < H; ++k) wl[k] = w_lin[o * H + k];
  }
  const float bl = b_lin[(lane < OUTN) ? lane : 0];

  float c0 = 0.0f, c1 = 0.0f;
  float sh0[H], sh1[H];
#pragma unroll
  for (int k = 0; k < H; ++k) { sh0[k] = 0.0f; sh1[k] = 0.0f; }

  float h0v = 0.0f, h1v = 0.0f;

  auto L0 = [&](float xw) {
    float a0 = xw, a1 = 0.0f, a2 = 0.0f;
#pragma unroll
    for (int k = 0; k < 5; ++k)   a0 = fmaf(w0[k], sh0[k], a0);
#pragma unroll
    for (int k = 5; k < 10; ++k)  a1 = fmaf(w0[k], sh0[k], a1);
#pragma unroll
    for (int k = 10; k < 15; ++k) a2 = fmaf(w0[k], sh0[k], a2);
    float a = a0 + (a1 + a2);
    float e = fast_exp2(a);
    float s = fast_rcp(1.0f + e);
    float v = fmaf(s, scv, offv);
    float vi = qbcast<0>(v), vf = qbcast<1>(v), vg = qbcast<2>(v), vo = qbcast<3>(v);
    c0 = fmaf(vf, c0, vi * vg);
    float th = fmaf(fast_rcp(1.0f + fast_exp2(c0)), 2.0f, -1.0f);
    h0v = vo * th;
  };
  auto L1 = [&]() {
    float u0 = bias1, u1 = 0.0f, u2 = 0.0f, u3 = 0.0f, u4 = 0.0f, u5 = 0.0f;
#pragma unroll
    for (int k = 0; k < 5; ++k)   { u0 = fmaf(wi1[k], sh0[k], u0); u3 = fmaf(wh1[k], sh1[k], u3); }
#pragma unroll
    for (int k = 5; k < 10; ++k)  { u1 = fmaf(wi1[k], sh0[k], u1); u4 = fmaf(wh1[k], sh1[k], u4); }
#pragma unroll
    for (int k = 10; k < 15; ++k) { u2 = fmaf(wi1[k], sh0[k], u2); u5 = fmaf(wh1[k], sh1[k], u5); }
    float b = ((u0 + u1) + (u2 + u3)) + (u4 + u5);
    float e = fast_exp2(b);
    float s = fast_rcp(1.0f + e);
    float v = fmaf(s, scv, offv);
    float qi = qbcast<0>(v), qf = qbcast<1>(v), qg = qbcast<2>(v), qo = qbcast<3>(v);
    c1 = fmaf(qf, c1, qi * qg);
    float th = fmaf(fast_rcp(1.0f + fast_exp2(c1)), 2.0f, -1.0f);
    h1v = qo * th;
  };
  auto B0 = [&]() {
#pragma unroll
    for (int k = 0; k < H; ++k) sh0[k] = rl(h0v, 4 * k);
  };
  auto B1 = [&]() {
#pragma unroll
    for (int k = 0; k < H; ++k) sh1[k] = rl(h1v, 4 * k);
  };
  auto LIN = [&](int t2) {   // fallback only (h1g == nullptr)
    float o0 = bl, o1 = 0.0f, o2 = 0.0f;
#pragma unroll
    for (int k = 0; k < 5; ++k)   o0 = fmaf(wl[k], sh1[k], o0);
#pragma unroll
    for (int k = 5; k < 10; ++k)  o1 = fmaf(wl[k], sh1[k], o1);
#pragma unroll
    for (int k = 10; k < 15; ++k) o2 = fmaf(wl[k], sh1[k], o2);
    if (lane < OUTN) out[t2 * OUTN + lane] = o0 + (o1 + o2);
  };

  // prologue: i = 0 (L0 only)
  float xw_cur = xw0[g];
  float xw_n1  = xw0[1 * G4 + g];
  L0(xw_cur);
  B0();
  xw_cur = xw_n1;
  xw_n1  = xw0[2 * G4 + g];

  // main loop: i = 1 .. T-1
  for (int i = 1; i < T_SEQ; ++i) {
    int tn = (i + 2 < T_SEQ) ? (i + 2) : 0;
    float xw_n2 = xw0[tn * G4 + g];

    L1();                                 // h1[i-1]
    L0(xw_cur);                           // h0[i]
    if (h1g) h1g[(i - 1) * 16 + j] = h1v; // store h1[i-1] (all lanes; j=15 pad)

    B0();
    B1();
    if (!h1g) LIN(i - 1);                 // fallback path only

    xw_cur = xw_n1;
    xw_n1  = xw_n2;
  }

  // epilogue: step T-1 of layer 1
  L1();
  if (h1g) {
    h1g[(T_SEQ - 1) * 16 + j] = h1v;
  } else {
    B1();
    LIN(T_SEQ - 1);
  }
}

// ---------- kernel C: LIN epilogue (parallel over t) ----------
__global__ void __launch_bounds__(64, 1)
lin_out(const float* __restrict__ h1g,
        const float* __restrict__ w_lin,
        const float* __restrict__ b_lin,
        float* __restrict__ out) {
  const int t = blockIdx.x;
  const int o = threadIdx.x;
  if (o >= OUTN) return;
  const float* hp = h1g + t * 16;
  float wl[H];
#pragma unroll
  for (int k = 0; k < H; ++k) wl[k] = w_lin[o * H + k];
  float o0 = b_lin[o], o1 = 0.0f, o2 = 0.0f;
#pragma unroll
  for (int k = 0; k < 5; ++k)   o0 = fmaf(wl[k], hp[k], o0);
#pragma unroll
  for (int k = 5; k < 10; ++k)  o1 = fmaf(wl[k], hp[k], o1);
#pragma unroll
  for (int k = 10; k < 15; ++k) o2 = fmaf(wl[k], hp[k], o2);
  out[t * OUTN + o] = o0 + (o1 + o2);
}

// ---------- launch ----------
extern "C" void kernel_launch(void* const* d_in, const int* in_sizes, int n_in,
                              void* d_out, int out_size, void* d_ws, size_t ws_size,
                              hipStream_t stream) {
  const float* x     = (const float*)d_in[0];
  const float* w_ih0 = (const float*)d_in[1];
  const float* w_hh0 = (const float*)d_in[2];
  const float* b_ih0 = (const float*)d_in[3];
  const float* b_hh0 = (const float*)d_in[4];
  const float* w_ih1 = (const float*)d_in[5];
  const float* w_hh1 = (const float*)d_in[6];
  const float* b_ih1 = (const float*)d_in[7];
  const float* b_hh1 = (const float*)d_in[8];
  const float* w_lin = (const float*)d_in[9];
  const float* b_lin = (const float*)d_in[10];
  float* out = (float*)d_out;
  float* xw0 = (float*)d_ws;  // 122880 B

  float* h1g = nullptr;
  if (ws_size >= (size_t)XW_BYTES + (size_t)H1_BYTES)
    h1g = (float*)((char*)d_ws + XW_BYTES);

  precompute_xw0<<<dim3((T_SEQ * G4 + 255) / 256), dim3(256), 0, stream>>>(
      x, w_ih0, b_ih0, b_hh0, xw0);
  // diagnostics: per-dispatch dur_us in rocprof = issue floor / chain floor
  probe_issue<<<dim3(1), dim3(64), 0, stream>>>(xw0);
  probe_chain<<<dim3(1), dim3(64), 0, stream>>>(xw0);
  lstm_main<<<dim3(1), dim3(64), 0, stream>>>(
      xw0, w_hh0, w_ih1, w_hh1, b_ih1, b_hh1, w_lin, b_lin, out, h1g);
  if (h1g)
    lin_out<<<dim3(T_SEQ), dim3(64), 0, stream>>>(h1g, w_lin, b_lin, out);
}